// Round 1
// baseline (658.423 us; speedup 1.0000x reference)
//
#include <hip/hip_runtime.h>
#include <stdint.h>

#define BH     64
#define SEQ    4096
#define DDIM   128
#define MDIM   128
#define NCHUNK 16
#define CHUNK  256        // SEQ / NCHUNK
#define TSROWS 32         // s-rows per LDS tile in kA
#define EPSV   1e-6f

typedef __attribute__((ext_vector_type(8))) short        bf16x8;
typedef __attribute__((ext_vector_type(4))) float        f32x4;
typedef __attribute__((ext_vector_type(4))) unsigned int u32x4;
typedef __attribute__((ext_vector_type(2))) unsigned int u32x2;

__device__ __forceinline__ unsigned int pack2bf(float lo, float hi) {
  unsigned int ul = __builtin_bit_cast(unsigned int, lo);
  unsigned int uh = __builtin_bit_cast(unsigned int, hi);
  ul = (ul + 0x7fffu + ((ul >> 16) & 1u)) >> 16;   // RNE f32->bf16
  uh = (uh + 0x7fffu + ((uh >> 16) & 1u)) >> 16;
  return ul | (uh << 16);
}

__device__ __forceinline__ float bf2f(unsigned short h) {
  unsigned int u = ((unsigned int)h) << 16;
  return __builtin_bit_cast(float, u);
}

// elu(x)+1 == x+1 (x>0) else exp(x)
__device__ __forceinline__ float phi_elu(float x) {
  return x > 0.f ? x + 1.f : __expf(x);
}

// ---------------- kernel I: init S_t from S_prev; zvec = SEQ*z_prev --------
__global__ void __launch_bounds__(256) kinit(const float* __restrict__ S_prev,
                                             const float* __restrict__ z_prev,
                                             float* __restrict__ S_t,
                                             float* __restrict__ zvec) {
  int gid = blockIdx.x * 256 + threadIdx.x;           // 262144 threads
  ((f32x4*)S_t)[gid] = ((const f32x4*)S_prev)[gid];
  if (gid < BH * DDIM) zvec[gid] = (float)SEQ * z_prev[gid];
}

// swizzled LDS offset (ushort units) for [128 rows][32 cols] bf16 tiles:
// row stride 32 shorts = 64B, 16B granules XOR'd with row&3 -> frag reads ~2-way
__device__ __forceinline__ int offA(int row, int col) {
  return row * 32 + ((((col >> 3) ^ row) & 3) << 3) + (col & 7);
}

// ---------------- kernel A: S_t += phi(k)^T v ; z_t ; zvec += ksum ----------
__global__ void __launch_bounds__(256) kA(const float* __restrict__ kg,
                                          const float* __restrict__ vg,
                                          const float* __restrict__ maskg,
                                          const float* __restrict__ z_prev,
                                          float* __restrict__ S_t,
                                          float* __restrict__ zvec,
                                          float* __restrict__ z_t) {
  __shared__ __align__(16) unsigned short kT[128 * 32];   // [d][s] bf16, swizzled
  __shared__ __align__(16) unsigned short vT[128 * 32];   // [m][s] bf16, swizzled
  __shared__ float ksum_l[128];

  const int t    = threadIdx.x;
  const int h    = blockIdx.y;          // 0..63
  const int c    = blockIdx.x;          // 0..15 s-chunk
  const int d    = t & 127;
  const int half = t >> 7;              // which 16-s half this thread stages
  const int w    = t >> 6;              // wave 0..3
  const int l    = t & 63;

  const float* kh = kg + (size_t)h * SEQ * DDIM;
  const float* vh = vg + (size_t)h * SEQ * DDIM;
  const float* mh = maskg + (size_t)h * SEQ;

  f32x4 acc[2][8];
  #pragma unroll
  for (int i = 0; i < 2; ++i)
    #pragma unroll
    for (int j = 0; j < 8; ++j) acc[i][j] = (f32x4){0.f, 0.f, 0.f, 0.f};

  float ksum = 0.f;

  // z_prev preload for z_t phase: dz = (t>>5) + 8*i
  float zpr[16];
  #pragma unroll
  for (int i = 0; i < 16; ++i) zpr[i] = z_prev[h * DDIM + (t >> 5) + 8 * i];

  const int rowa = l & 15;
  const int kgr  = l >> 4;

  for (int tile = 0; tile < CHUNK / TSROWS; ++tile) {
    const int s0 = c * CHUNK + tile * TSROWS;

    // ---- global loads (coalesced: 64 consecutive lanes = 256B along d) ----
    float kp[16], vp[16];
    #pragma unroll
    for (int j = 0; j < 16; ++j) {
      int s = s0 + half * 16 + j;
      float mval = mh[s];
      float kv   = kh[(size_t)s * DDIM + d];
      float ph   = phi_elu(kv) * mval;
      kp[j] = ph;
      ksum += ph;
      vp[j] = vh[(size_t)s * DDIM + d] * mval;
    }

    __syncthreads();   // previous tile's LDS fully consumed

    // ---- transposed bf16 LDS writes: thread owns column d, 16 s-values ----
    {
      u32x4 p0 = { pack2bf(kp[0], kp[1]),  pack2bf(kp[2], kp[3]),
                   pack2bf(kp[4], kp[5]),  pack2bf(kp[6], kp[7]) };
      u32x4 p1 = { pack2bf(kp[8], kp[9]),  pack2bf(kp[10], kp[11]),
                   pack2bf(kp[12], kp[13]), pack2bf(kp[14], kp[15]) };
      *(u32x4*)&kT[offA(d, half * 16)]     = p0;
      *(u32x4*)&kT[offA(d, half * 16 + 8)] = p1;
      u32x4 q0 = { pack2bf(vp[0], vp[1]),  pack2bf(vp[2], vp[3]),
                   pack2bf(vp[4], vp[5]),  pack2bf(vp[6], vp[7]) };
      u32x4 q1 = { pack2bf(vp[8], vp[9]),  pack2bf(vp[10], vp[11]),
                   pack2bf(vp[12], vp[13]), pack2bf(vp[14], vp[15]) };
      *(u32x4*)&vT[offA(d, half * 16)]     = q0;
      *(u32x4*)&vT[offA(d, half * 16 + 8)] = q1;
    }
    __syncthreads();

    // ---- z_t write from transposed tile (32 lanes x 4B = 128B coalesced) ----
    {
      const int sz  = t & 31;
      const int dz0 = t >> 5;
      #pragma unroll
      for (int i = 0; i < 16; ++i) {
        int dz = dz0 + 8 * i;
        float val = bf2f(kT[offA(dz, sz)]) + zpr[i];
        z_t[((size_t)h * DDIM + dz) * SEQ + s0 + sz] = val;
      }
    }

    // ---- MFMA: C[d][m] += kT^ * v, wave w owns d-strip [32w, 32w+32) ----
    {
      bf16x8 a[2], b[8];
      #pragma unroll
      for (int rb = 0; rb < 2; ++rb)
        a[rb] = *(const bf16x8*)&kT[offA(32 * w + 16 * rb + rowa, 8 * kgr)];
      #pragma unroll
      for (int mf = 0; mf < 8; ++mf)
        b[mf] = *(const bf16x8*)&vT[offA(16 * mf + rowa, 8 * kgr)];
      #pragma unroll
      for (int rb = 0; rb < 2; ++rb)
        #pragma unroll
        for (int mf = 0; mf < 8; ++mf)
          acc[rb][mf] = __builtin_amdgcn_mfma_f32_16x16x32_bf16(
              a[rb], b[mf], acc[rb][mf], 0, 0, 0);
    }
  }

  // ---- ksum -> zvec (combine halves, one atomic per d) ----
  if (half == 1) ksum_l[d] = ksum;
  __syncthreads();
  if (half == 0) atomicAdd(&zvec[h * DDIM + d], ksum + ksum_l[d]);

  // ---- S_t atomics (16 chunk-blocks accumulate into d_out S_t region) ----
  float* sth = S_t + (size_t)h * DDIM * MDIM;
  const int col0 = l & 15;
  const int r0   = (l >> 4) * 4;
  #pragma unroll
  for (int rb = 0; rb < 2; ++rb)
    #pragma unroll
    for (int r = 0; r < 4; ++r) {
      int row = 32 * w + 16 * rb + r0 + r;
      #pragma unroll
      for (int mf = 0; mf < 8; ++mf)
        atomicAdd(&sth[(size_t)row * MDIM + 16 * mf + col0], acc[rb][mf][r]);
    }
}

// ---------------- kernel R: S_t (f32 [d][m]) -> stT (bf16 [m][d]) ----------
__global__ void __launch_bounds__(256) kR(const float* __restrict__ S_t,
                                          unsigned short* __restrict__ stT) {
  __shared__ __align__(16) float sl[128 * 36];   // [d][32m strip], padded rows
  const int t     = threadIdx.x;
  const int h     = blockIdx.y;
  const int strip = blockIdx.x;                  // 0..3 (32 m-cols each)
  const float* sth = S_t + (size_t)h * DDIM * MDIM + strip * 32;
  #pragma unroll
  for (int i = 0; i < 4; ++i) {
    int x = i * 256 + t;
    int dd = x >> 3, m4 = x & 7;
    f32x4 vv = *(const f32x4*)&sth[(size_t)dd * MDIM + m4 * 4];
    *(f32x4*)&sl[dd * 36 + m4 * 4] = vv;
  }
  __syncthreads();
  unsigned short* dst = stT + (size_t)h * MDIM * DDIM + (size_t)strip * 32 * DDIM;
  #pragma unroll
  for (int i = 0; i < 16; ++i) {
    int x = i * 256 + t;
    int mm = x >> 7, dd = x & 127;
    unsigned int u = __builtin_bit_cast(unsigned int, sl[dd * 36 + mm]);
    u = (u + 0x7fffu + ((u >> 16) & 1u)) >> 16;
    dst[(size_t)mm * DDIM + dd] = (unsigned short)u;
  }
}

// swizzled LDS offset (ushort units) for [128][128] bf16: row stride 128
// shorts = 256B; 16B granule index g (0..15) XOR'd in its low 3 bits.
__device__ __forceinline__ int offB(int row, int g) {
  int gs = (g & 8) | ((g ^ row) & 7);
  return row * 128 + gs * 8;
}

// ---------------- kernel B: out = (phi(q) @ S_t) / (phi(q).zvec + eps) -----
__global__ void __launch_bounds__(256) kB(const float* __restrict__ qg,
                                          const unsigned short* __restrict__ stT,
                                          const float* __restrict__ zvec,
                                          float* __restrict__ outg) {
  __shared__ __align__(16) unsigned short qb[128 * 128];  // phi(q) [s][d]
  __shared__ __align__(16) unsigned short sb[128 * 128];  // S_t^T  [m][d]
  __shared__ float den_l[128];

  const int t  = threadIdx.x;
  const int h  = blockIdx.y;
  const int st = blockIdx.x;            // 0..31 s-tiles of 128
  const int s0 = st * 128;
  const int l  = t & 63;
  const int w  = t >> 6;

  // ---- stage S_t^T (bf16 from ws, L2/L3-resident) ----
  const unsigned short* sth = stT + (size_t)h * MDIM * DDIM;
  #pragma unroll
  for (int i = 0; i < 8; ++i) {
    int x = i * 256 + t;
    int row = x >> 4, g = x & 15;
    u32x4 vv = *(const u32x4*)&sth[row * 128 + g * 8];
    *(u32x4*)&sb[offB(row, g)] = vv;
  }

  // ---- stage phi(q) + den via 32-lane shuffle reduce ----
  const float* qh = qg + (size_t)h * SEQ * DDIM;
  const float* zv = zvec + h * DDIM;
  #pragma unroll
  for (int i = 0; i < 16; ++i) {
    int x = i * 256 + t;
    int row = x >> 5, c4 = x & 31;
    f32x4 qq = *(const f32x4*)&qh[(size_t)(s0 + row) * DDIM + c4 * 4];
    float p0 = phi_elu(qq[0]), p1 = phi_elu(qq[1]);
    float p2 = phi_elu(qq[2]), p3 = phi_elu(qq[3]);
    float dp = p0 * zv[c4 * 4 + 0] + p1 * zv[c4 * 4 + 1] +
               p2 * zv[c4 * 4 + 2] + p3 * zv[c4 * 4 + 3];
    #pragma unroll
    for (int o = 16; o >= 1; o >>= 1) dp += __shfl_xor(dp, o);
    if ((t & 31) == 0) den_l[row] = dp;
    u32x2 pk = { pack2bf(p0, p1), pack2bf(p2, p3) };
    *(u32x2*)&qb[offB(row, c4 >> 1) + (c4 & 1) * 4] = pk;
  }
  __syncthreads();

  // ---- MFMA: num[s][m]; wave w owns s-rows [32w, 32w+32) ----
  f32x4 acc[2][8];
  #pragma unroll
  for (int i = 0; i < 2; ++i)
    #pragma unroll
    for (int j = 0; j < 8; ++j) acc[i][j] = (f32x4){0.f, 0.f, 0.f, 0.f};

  const int rowa = l & 15;
  const int kgr  = l >> 4;
  #pragma unroll
  for (int kk = 0; kk < 4; ++kk) {
    bf16x8 a[2], b[8];
    #pragma unroll
    for (int rb = 0; rb < 2; ++rb) {
      int r = 32 * w + 16 * rb + rowa;
      a[rb] = *(const bf16x8*)&qb[offB(r, 4 * kk + kgr)];
    }
    #pragma unroll
    for (int mf = 0; mf < 8; ++mf) {
      int r = 16 * mf + rowa;
      b[mf] = *(const bf16x8*)&sb[offB(r, 4 * kk + kgr)];
    }
    #pragma unroll
    for (int rb = 0; rb < 2; ++rb)
      #pragma unroll
      for (int mf = 0; mf < 8; ++mf)
        acc[rb][mf] = __builtin_amdgcn_mfma_f32_16x16x32_bf16(
            a[rb], b[mf], acc[rb][mf], 0, 0, 0);
  }

  // ---- epilogue: divide by den, store ----
  float* oh = outg + (size_t)h * SEQ * MDIM + (size_t)s0 * MDIM;
  const int col0 = l & 15;
  const int r0   = (l >> 4) * 4;
  #pragma unroll
  for (int rb = 0; rb < 2; ++rb)
    #pragma unroll
    for (int r = 0; r < 4; ++r) {
      int row = 32 * w + 16 * rb + r0 + r;
      float inv = 1.f / (den_l[row] + EPSV);
      #pragma unroll
      for (int mf = 0; mf < 8; ++mf)
        oh[(size_t)row * MDIM + 16 * mf + col0] = acc[rb][mf][r] * inv;
    }
}

extern "C" void kernel_launch(void* const* d_in, const int* in_sizes, int n_in,
                              void* d_out, int out_size, void* d_ws, size_t ws_size,
                              hipStream_t stream) {
  const float* q      = (const float*)d_in[0];
  const float* k      = (const float*)d_in[1];
  const float* v      = (const float*)d_in[2];
  const float* mask   = (const float*)d_in[3];
  const float* S_prev = (const float*)d_in[4];
  const float* z_prev = (const float*)d_in[5];

  float* out = (float*)d_out;                             // [64,4096,128]
  float* S_t = out + (size_t)BH * SEQ * MDIM;             // [64,128,128]
  float* z_t = S_t + (size_t)BH * DDIM * MDIM;            // [64,128,4096]

  unsigned short* stT = (unsigned short*)d_ws;            // 2 MB bf16 [h][m][d]
  float* zvec = (float*)((char*)d_ws + (size_t)BH * MDIM * DDIM * 2);  // 32 KB

  kinit<<<dim3((BH * DDIM * MDIM / 4) / 256), 256, 0, stream>>>(S_prev, z_prev, S_t, zvec);
  kA<<<dim3(NCHUNK, BH), 256, 0, stream>>>(k, v, mask, z_prev, S_t, zvec, z_t);
  kR<<<dim3(4, BH), 256, 0, stream>>>(S_t, stT);
  kB<<<dim3(32, BH), 256, 0, stream>>>(q, stT, zvec, out);
}